// Round 2
// baseline (1358.515 us; speedup 1.0000x reference)
//
#include <hip/hip_runtime.h>
#include <hip/hip_bf16.h>

// CGCNN forward, MFMA conv GEMM (R10).
//   g[e,:] = [x[n(e)] | x[nb(e)] | bond(e)] @ Wf + b  (K=169 pad 192, N=128)
// R10 vs R9: R9's register double-buffer SPILLED (WRITE_SIZE +43MB, VGPR
// capped 128) and both R8/R9 serialize A-fragment loads at ~800cyc each
// (14K cyc/supertile measured). R10 moves staging to LDS via
// __builtin_amdgcn_global_load_lds (block-level async DMA, 3 insts/supertile
// instead of 72 per-wave loads):
//   - bond_pad global layout rewritten FRAGMENT-MAJOR (bond_prep) so DMA is
//     linear and ds_read_b128 is base+lane*16 (conflict-free).
//   - neighbor xh rows gathered fragment-major via per-lane DMA source addrs
//     (LDS dest stays linear per the global_load_lds constraint).
//   - double-buffered; one __syncthreads per supertile (vmcnt(0) drain is
//     intended: DMA for s+1 has the whole iteration to complete).
//   - ACT mid-barrier is raw s_barrier + lgkmcnt-only wait so DMA stays in
//     flight across it.
// R7 LDS-staging fallback kept for ws_size < 108.5 MB.

#define NATOM 60000
#define MNBR  12
#define F0D   92
#define FBD   41
#define FD    64
#define F2D   128
#define NCRY  2000
#define HD    128
#define NSUP  15000          // 720000 edges / 48
#define GS    132            // gbuf row stride (floats)
#define CGRID 3000           // conv grid; NSUP/CGRID == 5 exactly

// ws layout (float units)
#define OFF_X      0ull          // 3,840,000 f32
#define OFF_XH     3840000ull    // 3,840,000 u16
#define OFF_SUMMED 5760000ull    // 3,840,000 f32
#define OFF_STATS  9600000ull    // sum1[128] sq1[128] sum2[64] sq2[64]
#define OFF_CRYS   9600384ull
#define OFF_CNT    9728384ull
#define OFF_WCONV  9730384ull    // 80,833 f32
#define OFF_WBF    9811220ull    // 73,728 u16 = 36,864 f slots
#define OFF_FLAG   9848084ull
#define WS_NEED_BYTES (9848085ull * 4ull)
#define OFF_BPAD   9848088ull    // 34,560,000 u16 = 17,280,000 f slots (16B aligned)
#define WS_FULL_BYTES ((OFF_BPAD + 17280000ull) * 4ull)   // 108,512,352

// offsets inside wconv
#define W_EMB_O  0
#define B_EMB_O  5888
#define W_FULL_O 5952
#define B_FULL_O 70848
#define G1_O     71232
#define BE1_O    71616
#define G2_O     72000
#define BE2_O    72192
#define W_FC_O   72384
#define B_FC_O   80576
#define W_OUT_O  80704
#define B_OUT_O  80832
#define WC_TOTAL 80833

typedef unsigned short u16;
typedef __attribute__((ext_vector_type(8))) short bf16x8;
typedef __attribute__((ext_vector_type(4))) float f32x4;

__device__ __forceinline__ float bf2f(u16 u){
  union { unsigned int i; float f; } v; v.i = ((unsigned int)u) << 16; return v.f;
}
__device__ __forceinline__ u16 f2bf(float f){
  union { float f; unsigned int i; } v; v.f = f;
  unsigned int x = v.i;
  return (u16)((x + 0x7FFFu + ((x >> 16) & 1u)) >> 16);
}
__device__ __forceinline__ float softplusf_(float x){
  return fmaxf(x, 0.f) + log1pf(expf(-fabsf(x)));
}
__device__ __forceinline__ float softplus_fast(float x){
  return fmaxf(x, 0.f) + __logf(1.f + __expf(-fabsf(x)));
}
__device__ __forceinline__ float sigmoid_fast(float x){
  return __builtin_amdgcn_rcpf(1.f + __expf(-x));
}

// async global->LDS DMA, 16B per lane. LDS dest = wave-uniform base + lane*16,
// global source is per-lane.
typedef const __attribute__((address_space(1))) unsigned int* gup;
typedef __attribute__((address_space(3))) unsigned int* lup;
__device__ __forceinline__ void dma16(const void* g, void* l){
  __builtin_amdgcn_global_load_lds((gup)g, (lup)l, 16, 0, 0);
}

__global__ __launch_bounds__(64) void detect_kernel(
    const u16* __restrict__ data, int* __restrict__ flag){
  int tid = threadIdx.x;
  float v = bf2f(data[tid * 2]);
  float av = fabsf(v);
  bool sane = (av > 1e-6f) && (av < 100.f);
  unsigned long long m = __ballot(sane);
  if (tid == 0) *flag = (__popcll(m) >= 32) ? 1 : 0;
}

struct CvtArgs {
  const void* src[12];
  int start[13];
};

__global__ __launch_bounds__(256) void cvt_all_kernel(
    CvtArgs a, float* __restrict__ dst, const int* __restrict__ flag){
  int i = blockIdx.x * 256 + threadIdx.x;
  if (i >= WC_TOTAL) return;
  int r = 0;
  while (i >= a.start[r + 1]) r++;
  int rel = i - a.start[r];
  if (*flag) dst[i] = bf2f(((const u16*)a.src[r])[rel]);
  else       dst[i] = ((const float*)a.src[r])[rel];
}

__global__ __launch_bounds__(256) void build_bfrag(
    const float* __restrict__ wfull, u16* __restrict__ wbf){
  int t = blockIdx.x * 256 + threadIdx.x;
  if (t >= 3 * 6 * 8 * 64) return;
  int lane = t & 63, nt = (t >> 6) & 7, c = (t >> 9) % 6, layer = t / 3072;
  int q = lane >> 4, nloc = lane & 15;
  u16 vals[8];
  #pragma unroll
  for (int i = 0; i < 8; i++){
    int k = c * 32 + q * 8 + i;
    float v = (k < 169) ? wfull[layer * 169 * F2D + k * F2D + nt * 16 + nloc] : 0.f;
    vals[i] = f2bf(v);
  }
  *(uint4*)&wbf[(size_t)t * 8] = *(uint4*)vals;
}

// One-time repack, FRAGMENT-MAJOR per supertile (288 16B slots):
//   slot j: et=j/96, jj=j%96
//     jj<64 : chunk4 — lane=jj,    row=et*16+(lane&15), feats (lane>>4)*8..+7
//     jj>=64: chunk5 — l2=jj-64,   row=et*16+(l2&15),   feats 32+(l2>>4)*8..+7
// so conv's ds_read_b128 at base + (et*96 [+64] + lane)*16 is conflict-free
// and the staging DMA source is a pure linear copy.
__global__ __launch_bounds__(256) void bond_prep(
    const void* __restrict__ nbr_fea, u16* __restrict__ bond_pad,
    const int* __restrict__ flag){
  __shared__ __align__(16) char sm[7872];
  u16*   lb_u = (u16*)sm;
  float* lb_f = (float*)sm;
  int s = blockIdx.x, tid = threadIdx.x;
  const int isbf = *flag;
  if (isbf){
    const uint4* src = (const uint4*)((const u16*)nbr_fea + (size_t)s * 1968);
    if (tid < 246) ((uint4*)sm)[tid] = src[tid];
  } else {
    const uint4* src = (const uint4*)((const float*)nbr_fea + (size_t)s * 1968);
    for (int t = tid; t < 492; t += 256) ((uint4*)sm)[t] = src[t];
  }
  __syncthreads();
  uint4* outv = (uint4*)(bond_pad + (size_t)s * 2304);
  for (int slot = tid; slot < 288; slot += 256){
    int et = slot / 96, jj = slot - et * 96;
    int l  = (jj < 64) ? jj : (jj - 64);
    int row = et * 16 + (l & 15);
    int kb  = ((jj < 64) ? 0 : 32) + (l >> 4) * 8;
    u16 v[8];
    #pragma unroll
    for (int i = 0; i < 8; i++){
      int k = kb + i;
      v[i] = (k < FBD) ? (isbf ? lb_u[row * FBD + k] : f2bf(lb_f[row * FBD + k])) : (u16)0;
    }
    outv[slot] = *(uint4*)v;
  }
}

__global__ __launch_bounds__(256) void embed_kernel(
    const void* __restrict__ atom_fea, const float* __restrict__ W_emb,
    const float* __restrict__ b_emb, float* __restrict__ x,
    u16* __restrict__ xh, const int* __restrict__ flag){
  int tid = threadIdx.x;
  int n = blockIdx.x * 4 + (tid >> 6);
  int f = tid & 63;
  float acc = b_emb[f];
  if (*flag){
    const u16* arow = (const u16*)atom_fea + n * F0D;
    for (int k = 0; k < F0D; k++)
      acc = fmaf(bf2f(arow[k]), W_emb[k * FD + f], acc);
  } else {
    const float* arow = (const float*)atom_fea + n * F0D;
    for (int k = 0; k < F0D; k++)
      acc = fmaf(arow[k], W_emb[k * FD + f], acc);
  }
  x[n * FD + f] = acc;
  xh[n * FD + f] = f2bf(acc);
}

// ---------------------------------------------------------------------------
// R10: LDS-staged conv pass. Per supertile, per-buffer LDS (11264 B):
//   [0,4608)     bond fragment-major (288 slots, linear from bond_pad)
//   [4608,5120)  xself: 4 atom rows x 128 B (linear from xh)
//   [5120,11264) xnbr fragment-major: (et,ch,lane) -> xh[nb[et*16+nloc]]
//                bytes (ch*4+q)*16, gathered via per-lane DMA source.
// Staged in 3 wave-aligned rounds: 256 + 256 + 192 slots.
// ---------------------------------------------------------------------------
template<int ACT>
__global__ __launch_bounds__(256, ACT ? 3 : 4) void conv_lds(
    const u16* __restrict__ xh, const u16* __restrict__ bond_pad,
    const int* __restrict__ nbr_idx, const u16* __restrict__ wbf_l,
    const float* __restrict__ bfull, const float* __restrict__ sum1,
    const float* __restrict__ sq1, const float* __restrict__ g1,
    const float* __restrict__ be1, float* __restrict__ summed,
    float* __restrict__ o_sum, float* __restrict__ o_sq){
  extern __shared__ char smem[];
  char* stg  = smem;                                  // 2 x 11264
  float* gbuf = (float*)(smem + 22528);               // ACT only: 48*GS
  float* redS = ACT ? (float*)(smem + 22528 + 48 * GS * 4)
                    : (float*)(smem + 22528);
  float* redQ = redS + (ACT ? 64 : 128);

  const int tid = threadIdx.x;
  const int w = tid >> 6, lane = tid & 63;
  const int q = lane >> 4, nloc = lane & 15;

  bf16x8 Bf[6][2];
  const bf16x8* Bv = (const bf16x8*)wbf_l;
  #pragma unroll
  for (int c = 0; c < 6; c++)
    #pragma unroll
    for (int t2 = 0; t2 < 2; t2++)
      Bf[c][t2] = Bv[(c * 8 + w * 2 + t2) * 64 + lane];
  float bias0 = bfull[w * 32 + nloc];
  float bias1 = bfull[w * 32 + 16 + nloc];

  float A0 = 0.f, B0 = 0.f, A1 = 0.f, B1 = 0.f;
  if (ACT){
    const float invR = 1.f / (float)(NATOM * MNBR);
    float m0 = sum1[lane] * invR;
    float v0 = fmaxf(sq1[lane] * invR - m0 * m0, 0.f);
    A0 = g1[lane] * rsqrtf(v0 + 1e-5f);  B0 = be1[lane] - m0 * A0;
    float m1 = sum1[64 + lane] * invR;
    float v1 = fmaxf(sq1[64 + lane] * invR - m1 * m1, 0.f);
    A1 = g1[64 + lane] * rsqrtf(v1 + 1e-5f);  B1 = be1[64 + lane] - m1 * A1;
  }
  float sAcc0 = 0.f, sAcc1 = 0.f, qAcc0 = 0.f, qAcc1 = 0.f;
  if (tid < (ACT ? 64 : 128)){ redS[tid] = 0.f; redQ[tid] = 0.f; }

  // per-thread staging parameters
  const char* xh8   = (const char*)xh;
  const char* bpad8 = (const char*)bond_pad;
  const int jx1 = tid - 64;                    // round-1 xnbr (tid>=64)
  const int rA  = (tid >= 64) ? ((jx1 >> 7) * 16 + (jx1 & 15)) : 0;
  const int cg1 = (tid >= 64) ? (((((jx1 >> 6) & 1) << 2) + ((jx1 >> 4) & 3)) << 4) : 0;
  const int jx2 = tid + 192;                   // round-2 xnbr (tid<192, waves 0..2)
  const int rB  = (tid < 192) ? ((jx2 >> 7) * 16 + (jx2 & 15)) : 0;
  const int cg2 = (tid < 192) ? (((((jx2 >> 6) & 1) << 2) + ((jx2 >> 4) & 3)) << 4) : 0;

#define STAGE(DBUF, SS, NA, NB)                                                  \
  {                                                                              \
    const char* g0 = bpad8 + (size_t)(SS) * 4608 + (size_t)tid * 16;             \
    dma16(g0, (DBUF) + w * 1024);                                                \
    const char* g1p;                                                             \
    if (tid < 32)      g1p = bpad8 + (size_t)(SS) * 4608 + (size_t)(tid + 256) * 16; \
    else if (tid < 64) g1p = xh8 + (size_t)(SS) * 512 + (size_t)(tid - 32) * 16; \
    else               g1p = xh8 + (size_t)(NA) * 128 + cg1;                     \
    dma16(g1p, (DBUF) + 4096 + w * 1024);                                        \
    if (w < 3){                                                                  \
      const char* g2p = xh8 + (size_t)(NB) * 128 + cg2;                          \
      dma16(g2p, (DBUF) + 8192 + w * 1024);                                      \
    }                                                                            \
  }

  const bf16x8 zero8 = {0,0,0,0,0,0,0,0};
  const int s0 = blockIdx.x;

  // prologue: stage s0, prefetch indices for s0+CGRID
  int nbA = nbr_idx[s0 * 48 + rA];
  int nbB = nbr_idx[s0 * 48 + rB];
  STAGE(stg, s0, nbA, nbB);
  nbA = nbr_idx[(s0 + CGRID) * 48 + rA];
  nbB = nbr_idx[(s0 + CGRID) * 48 + rB];
  __syncthreads();   // drains DMA(s0) + idx loads; buf0 ready

  for (int k = 0; k < 5; k++){
    const int s = s0 + k * CGRID;
    char* cb   = stg + (k & 1) * 11264;
    char* nbuf = stg + ((k & 1) ^ 1) * 11264;
    if (k < 4) STAGE(nbuf, s + CGRID, nbA, nbB);
    if (k < 3){
      nbA = nbr_idx[(s + 2 * CGRID) * 48 + rA];
      nbB = nbr_idx[(s + 2 * CGRID) * 48 + rB];
    }
    #pragma unroll
    for (int et = 0; et < 3; et++){
      int naloc = (et * 16 + nloc) / 12;
      const char* xs = cb + 4608 + naloc * 128;
      bf16x8 a0 = *(const bf16x8*)(xs + q * 16);
      bf16x8 a1 = *(const bf16x8*)(xs + 64 + q * 16);
      bf16x8 a2 = *(const bf16x8*)(cb + 5120 + (et * 128 + lane) * 16);
      bf16x8 a3 = *(const bf16x8*)(cb + 5120 + (et * 128 + 64 + lane) * 16);
      bf16x8 a4 = *(const bf16x8*)(cb + (et * 96 + lane) * 16);
      bf16x8 a5 = (lane < 32) ? *(const bf16x8*)(cb + (et * 96 + 64 + lane) * 16)
                              : zero8;
      #pragma unroll
      for (int t2 = 0; t2 < 2; t2++){
        float bs = t2 ? bias1 : bias0;
        f32x4 acc = {bs, bs, bs, bs};
        acc = __builtin_amdgcn_mfma_f32_16x16x32_bf16(a0, Bf[0][t2], acc, 0, 0, 0);
        acc = __builtin_amdgcn_mfma_f32_16x16x32_bf16(a1, Bf[1][t2], acc, 0, 0, 0);
        acc = __builtin_amdgcn_mfma_f32_16x16x32_bf16(a2, Bf[2][t2], acc, 0, 0, 0);
        acc = __builtin_amdgcn_mfma_f32_16x16x32_bf16(a3, Bf[3][t2], acc, 0, 0, 0);
        acc = __builtin_amdgcn_mfma_f32_16x16x32_bf16(a4, Bf[4][t2], acc, 0, 0, 0);
        acc = __builtin_amdgcn_mfma_f32_16x16x32_bf16(a5, Bf[5][t2], acc, 0, 0, 0);
        if (ACT){
          int col = w * 32 + t2 * 16 + nloc;
          int r0 = et * 16 + q * 4;
          gbuf[(r0 + 0) * GS + col] = acc[0];
          gbuf[(r0 + 1) * GS + col] = acc[1];
          gbuf[(r0 + 2) * GS + col] = acc[2];
          gbuf[(r0 + 3) * GS + col] = acc[3];
        } else {
          float ss = acc[0] + acc[1] + acc[2] + acc[3];
          float qq = acc[0]*acc[0] + acc[1]*acc[1] + acc[2]*acc[2] + acc[3]*acc[3];
          if (t2){ sAcc1 += ss; qAcc1 += qq; } else { sAcc0 += ss; qAcc0 += qq; }
        }
      }
    }
    if (ACT){
      // gbuf ready: writers drain LDS, then raw barrier. DMA (vmcnt) for s+1
      // stays in flight and completes under the ACT phase below.
      __builtin_amdgcn_sched_barrier(0);
      asm volatile("s_waitcnt lgkmcnt(0)");
      __builtin_amdgcn_s_barrier();
      __builtin_amdgcn_sched_barrier(0);
      float p = 0.f;
      #pragma unroll
      for (int m = 0; m < 12; m++){
        int el = w * 12 + m;
        float u = fmaf(gbuf[el * GS + lane],      A0, B0);
        float v = fmaf(gbuf[el * GS + 64 + lane], A1, B1);
        p = fmaf(sigmoid_fast(u), softplus_fast(v), p);
      }
      summed[(s * 4 + w) * 64 + lane] = p;
      sAcc0 += p;  qAcc0 = fmaf(p, p, qAcc0);
    }
    // end of iteration: vmcnt(0)+lgkmcnt(0)+barrier — DMA(s+1) complete,
    // gbuf reads retired, buffers safely swappable.
    __syncthreads();
  }
#undef STAGE

  if (ACT){
    atomicAdd(&redS[lane], sAcc0);
    atomicAdd(&redQ[lane], qAcc0);
    __syncthreads();
    if (tid < 64){ atomicAdd(&o_sum[tid], redS[tid]); atomicAdd(&o_sq[tid], redQ[tid]); }
  } else {
    int c0 = w * 32 + nloc;
    atomicAdd(&redS[c0], sAcc0);       atomicAdd(&redQ[c0], qAcc0);
    atomicAdd(&redS[c0 + 16], sAcc1);  atomicAdd(&redQ[c0 + 16], qAcc1);
    __syncthreads();
    if (tid < 128){ atomicAdd(&o_sum[tid], redS[tid]); atomicAdd(&o_sq[tid], redQ[tid]); }
  }
}

// R7 fallback conv pass (small-ws path; reads raw nbr_fea, no bond_pad).
template<int ACT>
__global__ __launch_bounds__(256, 3) void conv_mfma(
    const u16* __restrict__ xh, const void* __restrict__ nbr_fea,
    const int* __restrict__ nbr_idx, const u16* __restrict__ wbf_l,
    const float* __restrict__ bfull, const float* __restrict__ sum1,
    const float* __restrict__ sq1, const float* __restrict__ g1,
    const float* __restrict__ be1, float* __restrict__ summed,
    float* __restrict__ o_sum, float* __restrict__ o_sq,
    const int* __restrict__ flag){
  extern __shared__ char smem[];
  u16*   fragA = (u16*)smem;                      // 6*512 u16
  float* gbuf  = (float*)(smem + 6144);           // ACT only: 48*GS
  float* redS  = ACT ? (gbuf + 48 * GS) : (float*)(smem + 6144);
  float* redQ  = redS + (ACT ? 64 : 128);

  const int tid = threadIdx.x;
  const int w = tid >> 6, lane = tid & 63;
  const int q = lane >> 4, nloc = lane & 15, q8 = q * 8;
  const int isbf = *flag;

  bf16x8 Bf[6][2];
  const bf16x8* Bv = (const bf16x8*)wbf_l;
  #pragma unroll
  for (int c = 0; c < 6; c++)
    #pragma unroll
    for (int t2 = 0; t2 < 2; t2++)
      Bf[c][t2] = Bv[(c * 8 + w * 2 + t2) * 64 + lane];
  float bias0 = bfull[w * 32 + nloc];
  float bias1 = bfull[w * 32 + 16 + nloc];

  float A0 = 0.f, B0 = 0.f, A1 = 0.f, B1 = 0.f;
  if (ACT){
    const float invR = 1.f / (float)(NATOM * MNBR);
    float m0 = sum1[lane] * invR;
    float v0 = fmaxf(sq1[lane] * invR - m0 * m0, 0.f);
    A0 = g1[lane] * rsqrtf(v0 + 1e-5f);  B0 = be1[lane] - m0 * A0;
    float m1 = sum1[64 + lane] * invR;
    float v1 = fmaxf(sq1[64 + lane] * invR - m1 * m1, 0.f);
    A1 = g1[64 + lane] * rsqrtf(v1 + 1e-5f);  B1 = be1[64 + lane] - m1 * A1;
  }
  float sAcc0 = 0.f, sAcc1 = 0.f, qAcc0 = 0.f, qAcc1 = 0.f;
  if (tid < (ACT ? 64 : 128)){ redS[tid] = 0.f; redQ[tid] = 0.f; }

  const bf16x8* xv = (const bf16x8*)xh;
  for (int s = blockIdx.x; s < NSUP; s += gridDim.x){
    int e0 = s * 48 + nloc;
    int nb0 = nbr_idx[e0], nb1 = nbr_idx[e0 + 16], nb2 = nbr_idx[e0 + 32];
    bf16x8 Af[3][6];
    if (w < 3){
      size_t eg = (size_t)(s * 48 + w * 16 + nloc);
      u16 v4[8], v5[8];
      if (isbf){
        const u16* br = (const u16*)nbr_fea + eg * 41;
        #pragma unroll
        for (int i = 0; i < 8; i++) v4[i] = br[q8 + i];
        #pragma unroll
        for (int i = 0; i < 8; i++){
          int k5 = 32 + q8 + i;
          v5[i] = (k5 < 41) ? br[k5] : (u16)0;
        }
      } else {
        const float* br = (const float*)nbr_fea + eg * 41;
        #pragma unroll
        for (int i = 0; i < 8; i++) v4[i] = f2bf(br[q8 + i]);
        #pragma unroll
        for (int i = 0; i < 8; i++){
          int k5 = 32 + q8 + i;
          v5[i] = (k5 < 41) ? f2bf(br[k5]) : (u16)0;
        }
      }
      *(uint4*)&fragA[(w * 2 + 0) * 512 + lane * 8] = *(uint4*)v4;
      *(uint4*)&fragA[(w * 2 + 1) * 512 + lane * 8] = *(uint4*)v5;
    }
    __syncthreads();
    #pragma unroll
    for (int et = 0; et < 3; et++){
      int nb = (et == 0) ? nb0 : (et == 1) ? nb1 : nb2;
      int na = s * 4 + (et * 16 + nloc) / 12;
      Af[et][0] = xv[na * 8 + q];
      Af[et][1] = xv[na * 8 + 4 + q];
      Af[et][2] = xv[nb * 8 + q];
      Af[et][3] = xv[nb * 8 + 4 + q];
      Af[et][4] = *(bf16x8*)&fragA[(et * 2 + 0) * 512 + lane * 8];
      Af[et][5] = *(bf16x8*)&fragA[(et * 2 + 1) * 512 + lane * 8];
    }
    #pragma unroll
    for (int et = 0; et < 3; et++){
      #pragma unroll
      for (int t2 = 0; t2 < 2; t2++){
        float bs = t2 ? bias1 : bias0;
        f32x4 acc = {bs, bs, bs, bs};
        acc = __builtin_amdgcn_mfma_f32_16x16x32_bf16(Af[et][0], Bf[0][t2], acc, 0, 0, 0);
        acc = __builtin_amdgcn_mfma_f32_16x16x32_bf16(Af[et][1], Bf[1][t2], acc, 0, 0, 0);
        acc = __builtin_amdgcn_mfma_f32_16x16x32_bf16(Af[et][2], Bf[2][t2], acc, 0, 0, 0);
        acc = __builtin_amdgcn_mfma_f32_16x16x32_bf16(Af[et][3], Bf[3][t2], acc, 0, 0, 0);
        acc = __builtin_amdgcn_mfma_f32_16x16x32_bf16(Af[et][4], Bf[4][t2], acc, 0, 0, 0);
        acc = __builtin_amdgcn_mfma_f32_16x16x32_bf16(Af[et][5], Bf[5][t2], acc, 0, 0, 0);
        if (ACT){
          int col = w * 32 + t2 * 16 + nloc;
          int r0 = et * 16 + q * 4;
          gbuf[(r0 + 0) * GS + col] = acc[0];
          gbuf[(r0 + 1) * GS + col] = acc[1];
          gbuf[(r0 + 2) * GS + col] = acc[2];
          gbuf[(r0 + 3) * GS + col] = acc[3];
        } else {
          float ss = acc[0] + acc[1] + acc[2] + acc[3];
          float qq = acc[0]*acc[0] + acc[1]*acc[1] + acc[2]*acc[2] + acc[3]*acc[3];
          if (t2){ sAcc1 += ss; qAcc1 += qq; } else { sAcc0 += ss; qAcc0 += qq; }
        }
      }
    }
    if (ACT){
      __syncthreads();
      float p = 0.f;
      #pragma unroll
      for (int m = 0; m < 12; m++){
        int el = w * 12 + m;
        float u = fmaf(gbuf[el * GS + lane],      A0, B0);
        float v = fmaf(gbuf[el * GS + 64 + lane], A1, B1);
        p = fmaf(sigmoid_fast(u), softplus_fast(v), p);
      }
      summed[(s * 4 + w) * 64 + lane] = p;
      sAcc0 += p;  qAcc0 = fmaf(p, p, qAcc0);
    }
    __syncthreads();
  }
  if (ACT){
    atomicAdd(&redS[lane], sAcc0);
    atomicAdd(&redQ[lane], qAcc0);
    __syncthreads();
    if (tid < 64){ atomicAdd(&o_sum[tid], redS[tid]); atomicAdd(&o_sq[tid], redQ[tid]); }
  } else {
    int c0 = w * 32 + nloc;
    atomicAdd(&redS[c0], sAcc0);       atomicAdd(&redQ[c0], qAcc0);
    atomicAdd(&redS[c0 + 16], sAcc1);  atomicAdd(&redQ[c0 + 16], qAcc1);
    __syncthreads();
    if (tid < 128){ atomicAdd(&o_sum[tid], redS[tid]); atomicAdd(&o_sq[tid], redQ[tid]); }
  }
}

__global__ __launch_bounds__(256) void update_x_kernel(
    float* __restrict__ x, u16* __restrict__ xh,
    const float* __restrict__ summed,
    const float* __restrict__ sum2, const float* __restrict__ sq2,
    const float* __restrict__ g2, const float* __restrict__ be2){
  int idx = blockIdx.x * 256 + threadIdx.x;
  int f = idx & 63;
  const float invN = 1.f / (float)NATOM;
  float mean = sum2[f] * invN;
  float var  = fmaxf(sq2[f] * invN - mean * mean, 0.f);
  float a = g2[f] * rsqrtf(var + 1e-5f);
  float b = be2[f] - mean * a;
  float v = x[idx] + fmaf(summed[idx], a, b);
  float r = softplusf_(v);
  x[idx] = r;
  xh[idx] = f2bf(r);
}

__global__ __launch_bounds__(256) void pool_kernel(
    const float* __restrict__ x, const int* __restrict__ cidx,
    float* __restrict__ crys, float* __restrict__ cnt){
  int idx = blockIdx.x * 256 + threadIdx.x;
  int n = idx >> 6, f = idx & 63;
  int c = cidx[n];
  atomicAdd(&crys[c * FD + f], x[idx]);
  if (f == 0) atomicAdd(&cnt[c], 1.f);
}

__global__ __launch_bounds__(128) void head_kernel(
    const float* __restrict__ crys, const float* __restrict__ cnt,
    const float* __restrict__ W_fc, const float* __restrict__ b_fc,
    const float* __restrict__ W_out, const float* __restrict__ b_out,
    void* __restrict__ out, const int* __restrict__ flag){
  __shared__ float p_s[FD];
  __shared__ float red_s[HD];
  int c = blockIdx.x, tid = threadIdx.x;
  if (tid < FD){
    float ct = fmaxf(cnt[c], 1.f);
    p_s[tid] = softplusf_(crys[c * FD + tid] / ct);
  }
  __syncthreads();
  float acc = b_fc[tid];
  for (int k = 0; k < FD; k++)
    acc = fmaf(p_s[k], W_fc[k * HD + tid], acc);
  float h = softplusf_(acc);
  red_s[tid] = h * W_out[tid];
  __syncthreads();
  for (int s = HD / 2; s > 0; s >>= 1){
    if (tid < s) red_s[tid] += red_s[tid + s];
    __syncthreads();
  }
  if (tid == 0){
    float r = red_s[0] + b_out[0];
    if (*flag) ((u16*)out)[c] = f2bf(r);
    else       ((float*)out)[c] = r;
  }
}

extern "C" void kernel_launch(void* const* d_in, const int* in_sizes, int n_in,
                              void* d_out, int out_size, void* d_ws, size_t ws_size,
                              hipStream_t stream){
  if (ws_size < WS_NEED_BYTES) return;  // diagnostic: leaves d_out zeroed
  const bool full = (ws_size >= WS_FULL_BYTES);
  const void* atom_fea = d_in[0];
  const void* nbr_fea  = d_in[1];
  const int* nbr_idx   = (const int*)d_in[2];
  const int* cidx      = (const int*)d_in[3];

  float* ws     = (float*)d_ws;
  float* x      = ws + OFF_X;
  u16*   xh     = (u16*)(ws + OFF_XH);
  float* summed = ws + OFF_SUMMED;
  float* sum1   = ws + OFF_STATS;
  float* sq1    = sum1 + 128;
  float* sum2   = sq1 + 128;
  float* sq2    = sum2 + 64;
  float* crys   = ws + OFF_CRYS;
  float* cnt    = ws + OFF_CNT;
  float* wc     = ws + OFF_WCONV;
  u16*   wbf    = (u16*)(ws + OFF_WBF);
  int*   flag   = (int*)(ws + OFF_FLAG);
  u16*   bpad   = (u16*)(ws + OFF_BPAD);

  detect_kernel<<<1, 64, 0, stream>>>((const u16*)nbr_fea, flag);
  CvtArgs ca;
  const int srcidx[12] = {4,5,6,7,8,9,10,11,12,13,14,15};
  const int starts[13] = {W_EMB_O, B_EMB_O, W_FULL_O, B_FULL_O, G1_O, BE1_O,
                          G2_O, BE2_O, W_FC_O, B_FC_O, W_OUT_O, B_OUT_O, WC_TOTAL};
  for (int i = 0; i < 12; i++){ ca.src[i] = d_in[srcidx[i]]; ca.start[i] = starts[i]; }
  ca.start[12] = WC_TOTAL;
  cvt_all_kernel<<<(WC_TOTAL + 255) / 256, 256, 0, stream>>>(ca, wc, flag);
  build_bfrag<<<(9216 + 255) / 256, 256, 0, stream>>>(wc + W_FULL_O, wbf);
  if (full) bond_prep<<<NSUP, 256, 0, stream>>>(nbr_fea, bpad, flag);

  embed_kernel<<<NATOM / 4, 256, 0, stream>>>(atom_fea, wc + W_EMB_O, wc + B_EMB_O,
                                              x, xh, flag);
  const int LDS_STATS_L = 2 * 11264 + 2 * 128 * 4;            // 23552
  const int LDS_ACT_L   = 2 * 11264 + 48 * GS * 4 + 2 * 64 * 4; // 48384
  const int LDS_STATS_F = 6144 + 2 * 128 * 4;                 // 7168
  const int LDS_ACT_F   = 6144 + (48 * GS + 128) * 4;         // 32000
  for (int i = 0; i < 3; i++){
    const u16* wbf_l = wbf + (size_t)i * 3072 * 8;
    hipMemsetAsync(sum1, 0, 384 * sizeof(float), stream);
    if (full){
      conv_lds<0><<<CGRID, 256, LDS_STATS_L, stream>>>(xh, bpad, nbr_idx,
          wbf_l, wc + B_FULL_O + i * F2D, sum1, sq1, wc + G1_O + i * F2D,
          wc + BE1_O + i * F2D, summed, sum1, sq1);
      conv_lds<1><<<CGRID, 256, LDS_ACT_L, stream>>>(xh, bpad, nbr_idx,
          wbf_l, wc + B_FULL_O + i * F2D, sum1, sq1, wc + G1_O + i * F2D,
          wc + BE1_O + i * F2D, summed, sum2, sq2);
    } else {
      conv_mfma<0><<<CGRID, 256, LDS_STATS_F, stream>>>(xh, nbr_fea, nbr_idx,
          wbf_l, wc + B_FULL_O + i * F2D, sum1, sq1, wc + G1_O + i * F2D,
          wc + BE1_O + i * F2D, summed, sum1, sq1, flag);
      conv_mfma<1><<<CGRID, 256, LDS_ACT_F, stream>>>(xh, nbr_fea, nbr_idx,
          wbf_l, wc + B_FULL_O + i * F2D, sum1, sq1, wc + G1_O + i * F2D,
          wc + BE1_O + i * F2D, summed, sum2, sq2, flag);
    }
    update_x_kernel<<<(NATOM * FD) / 256, 256, 0, stream>>>(x, xh, summed, sum2, sq2,
        wc + G2_O + i * FD, wc + BE2_O + i * FD);
  }
  hipMemsetAsync(crys, 0, (NCRY * FD + NCRY) * sizeof(float), stream);
  pool_kernel<<<(NATOM * FD) / 256, 256, 0, stream>>>(x, cidx, crys, cnt);
  head_kernel<<<NCRY, 128, 0, stream>>>(crys, cnt, wc + W_FC_O, wc + B_FC_O,
      wc + W_OUT_O, wc + B_OUT_O, d_out, flag);
}

// Round 3
// 1066.025 us; speedup vs baseline: 1.2744x; 1.2744x over previous
//
#include <hip/hip_runtime.h>
#include <hip/hip_bf16.h>

// CGCNN forward, MFMA conv GEMM (R11).
//   g[e,:] = [x[n(e)] | x[nb(e)] | bond(e)] @ Wf + b  (K=169 pad 192, N=128)
// R11 vs R10: R10's global_load_lds staging spilled (launch_bounds(256,4)
// pushed VGPR cap to 64 < 48-VGPR Bf live-set -> 279MB scratch writes) and
// the 16B DMA gather over-fetched (392MB). R11 keeps R10's VERIFIED layout
// (fragment-major bond_pad, 11264B LDS buffers, identical read addressing)
// but stages via normal loads -> regs -> ds_write (T14 split):
//   - 3 independent 16B loads/thread issued at iteration TOP (full MLP,
//     normal cache path), ds_write at iteration BOTTOM -> MFMA+ACT phase
//     hides the latency; one LDS copy shared by all 4 waves.
//   - raw lgkmcnt-only + s_barrier at iteration end keeps next-iter global
//     loads in flight (no vmcnt drain).
//   - launch_bounds(256,3) BOTH variants; staging adds only 12 transient
//     VGPRs -> no spill (verify: WRITE_SIZE ~16.5MB ACT / ~0.5MB stats).
// R7 LDS-staging fallback kept for ws_size < 108.5 MB.

#define NATOM 60000
#define MNBR  12
#define F0D   92
#define FBD   41
#define FD    64
#define F2D   128
#define NCRY  2000
#define HD    128
#define NSUP  15000          // 720000 edges / 48
#define GS    132            // gbuf row stride (floats)
#define CGRID 3000           // conv grid; NSUP/CGRID == 5 exactly

// ws layout (float units)
#define OFF_X      0ull          // 3,840,000 f32
#define OFF_XH     3840000ull    // 3,840,000 u16
#define OFF_SUMMED 5760000ull    // 3,840,000 f32
#define OFF_STATS  9600000ull    // sum1[128] sq1[128] sum2[64] sq2[64]
#define OFF_CRYS   9600384ull
#define OFF_CNT    9728384ull
#define OFF_WCONV  9730384ull    // 80,833 f32
#define OFF_WBF    9811220ull    // 73,728 u16 = 36,864 f slots
#define OFF_FLAG   9848084ull
#define WS_NEED_BYTES (9848085ull * 4ull)
#define OFF_BPAD   9848088ull    // 34,560,000 u16 = 17,280,000 f slots (16B aligned)
#define WS_FULL_BYTES ((OFF_BPAD + 17280000ull) * 4ull)   // 108,512,352

// offsets inside wconv
#define W_EMB_O  0
#define B_EMB_O  5888
#define W_FULL_O 5952
#define B_FULL_O 70848
#define G1_O     71232
#define BE1_O    71616
#define G2_O     72000
#define BE2_O    72192
#define W_FC_O   72384
#define B_FC_O   80576
#define W_OUT_O  80704
#define B_OUT_O  80832
#define WC_TOTAL 80833

typedef unsigned short u16;
typedef __attribute__((ext_vector_type(8))) short bf16x8;
typedef __attribute__((ext_vector_type(4))) float f32x4;

__device__ __forceinline__ float bf2f(u16 u){
  union { unsigned int i; float f; } v; v.i = ((unsigned int)u) << 16; return v.f;
}
__device__ __forceinline__ u16 f2bf(float f){
  union { float f; unsigned int i; } v; v.f = f;
  unsigned int x = v.i;
  return (u16)((x + 0x7FFFu + ((x >> 16) & 1u)) >> 16);
}
__device__ __forceinline__ float softplusf_(float x){
  return fmaxf(x, 0.f) + log1pf(expf(-fabsf(x)));
}
__device__ __forceinline__ float softplus_fast(float x){
  return fmaxf(x, 0.f) + __logf(1.f + __expf(-fabsf(x)));
}
__device__ __forceinline__ float sigmoid_fast(float x){
  return __builtin_amdgcn_rcpf(1.f + __expf(-x));
}

__global__ __launch_bounds__(64) void detect_kernel(
    const u16* __restrict__ data, int* __restrict__ flag){
  int tid = threadIdx.x;
  float v = bf2f(data[tid * 2]);
  float av = fabsf(v);
  bool sane = (av > 1e-6f) && (av < 100.f);
  unsigned long long m = __ballot(sane);
  if (tid == 0) *flag = (__popcll(m) >= 32) ? 1 : 0;
}

struct CvtArgs {
  const void* src[12];
  int start[13];
};

__global__ __launch_bounds__(256) void cvt_all_kernel(
    CvtArgs a, float* __restrict__ dst, const int* __restrict__ flag){
  int i = blockIdx.x * 256 + threadIdx.x;
  if (i >= WC_TOTAL) return;
  int r = 0;
  while (i >= a.start[r + 1]) r++;
  int rel = i - a.start[r];
  if (*flag) dst[i] = bf2f(((const u16*)a.src[r])[rel]);
  else       dst[i] = ((const float*)a.src[r])[rel];
}

__global__ __launch_bounds__(256) void build_bfrag(
    const float* __restrict__ wfull, u16* __restrict__ wbf){
  int t = blockIdx.x * 256 + threadIdx.x;
  if (t >= 3 * 6 * 8 * 64) return;
  int lane = t & 63, nt = (t >> 6) & 7, c = (t >> 9) % 6, layer = t / 3072;
  int q = lane >> 4, nloc = lane & 15;
  u16 vals[8];
  #pragma unroll
  for (int i = 0; i < 8; i++){
    int k = c * 32 + q * 8 + i;
    float v = (k < 169) ? wfull[layer * 169 * F2D + k * F2D + nt * 16 + nloc] : 0.f;
    vals[i] = f2bf(v);
  }
  *(uint4*)&wbf[(size_t)t * 8] = *(uint4*)vals;
}

// One-time repack, FRAGMENT-MAJOR per supertile (288 16B slots):
//   slot j: et=j/96, jj=j%96
//     jj<64 : chunk4 — lane=jj,    row=et*16+(lane&15), feats (lane>>4)*8..+7
//     jj>=64: chunk5 — l2=jj-64,   row=et*16+(l2&15),   feats 32+(l2>>4)*8..+7
// (verified correct in R10)
__global__ __launch_bounds__(256) void bond_prep(
    const void* __restrict__ nbr_fea, u16* __restrict__ bond_pad,
    const int* __restrict__ flag){
  __shared__ __align__(16) char sm[7872];
  u16*   lb_u = (u16*)sm;
  float* lb_f = (float*)sm;
  int s = blockIdx.x, tid = threadIdx.x;
  const int isbf = *flag;
  if (isbf){
    const uint4* src = (const uint4*)((const u16*)nbr_fea + (size_t)s * 1968);
    if (tid < 246) ((uint4*)sm)[tid] = src[tid];
  } else {
    const uint4* src = (const uint4*)((const float*)nbr_fea + (size_t)s * 1968);
    for (int t = tid; t < 492; t += 256) ((uint4*)sm)[t] = src[t];
  }
  __syncthreads();
  uint4* outv = (uint4*)(bond_pad + (size_t)s * 2304);
  for (int slot = tid; slot < 288; slot += 256){
    int et = slot / 96, jj = slot - et * 96;
    int l  = (jj < 64) ? jj : (jj - 64);
    int row = et * 16 + (l & 15);
    int kb  = ((jj < 64) ? 0 : 32) + (l >> 4) * 8;
    u16 v[8];
    #pragma unroll
    for (int i = 0; i < 8; i++){
      int k = kb + i;
      v[i] = (k < FBD) ? (isbf ? lb_u[row * FBD + k] : f2bf(lb_f[row * FBD + k])) : (u16)0;
    }
    outv[slot] = *(uint4*)v;
  }
}

__global__ __launch_bounds__(256) void embed_kernel(
    const void* __restrict__ atom_fea, const float* __restrict__ W_emb,
    const float* __restrict__ b_emb, float* __restrict__ x,
    u16* __restrict__ xh, const int* __restrict__ flag){
  int tid = threadIdx.x;
  int n = blockIdx.x * 4 + (tid >> 6);
  int f = tid & 63;
  float acc = b_emb[f];
  if (*flag){
    const u16* arow = (const u16*)atom_fea + n * F0D;
    for (int k = 0; k < F0D; k++)
      acc = fmaf(bf2f(arow[k]), W_emb[k * FD + f], acc);
  } else {
    const float* arow = (const float*)atom_fea + n * F0D;
    for (int k = 0; k < F0D; k++)
      acc = fmaf(arow[k], W_emb[k * FD + f], acc);
  }
  x[n * FD + f] = acc;
  xh[n * FD + f] = f2bf(acc);
}

// ---------------------------------------------------------------------------
// R11: reg-staged LDS conv pass. Per-buffer LDS (11264 B), layout = R10:
//   [0,4608)     bond fragment-major (288 slots, linear from bond_pad)
//   [4608,5120)  xself: 4 atom rows x 128 B
//   [5120,11264) xnbr fragment-major (384 chunks): chunk j holds
//                xh[nb[r(j)]] bytes c(j)..c(j)+16, r(j)=(j>>7)*16+(j&15),
//                c(j)=(((j>>6)&1)*4+((j>>4)&3))*16
// Staging: thread t loads slots {bond t} + {S1: t<32 bond 256+t | t<64
// xself t-32 | else xnbr t-64} + {t<192: xnbr t+192} into regs at iter top,
// ds_writes them to the other buffer at iter bottom.
// ---------------------------------------------------------------------------
template<int ACT>
__global__ __launch_bounds__(256, 3) void conv_lds(
    const u16* __restrict__ xh, const u16* __restrict__ bond_pad,
    const int* __restrict__ nbr_idx, const u16* __restrict__ wbf_l,
    const float* __restrict__ bfull, const float* __restrict__ sum1,
    const float* __restrict__ sq1, const float* __restrict__ g1,
    const float* __restrict__ be1, float* __restrict__ summed,
    float* __restrict__ o_sum, float* __restrict__ o_sq){
  extern __shared__ char smem[];
  char* stg  = smem;                                  // 2 x 11264
  float* gbuf = (float*)(smem + 22528);               // ACT only: 48*GS
  float* redS = ACT ? (float*)(smem + 22528 + 48 * GS * 4)
                    : (float*)(smem + 22528);
  float* redQ = redS + (ACT ? 64 : 128);

  const int tid = threadIdx.x;
  const int w = tid >> 6, lane = tid & 63;
  const int q = lane >> 4, nloc = lane & 15;

  bf16x8 Bf[6][2];
  const bf16x8* Bv = (const bf16x8*)wbf_l;
  #pragma unroll
  for (int c = 0; c < 6; c++)
    #pragma unroll
    for (int t2 = 0; t2 < 2; t2++)
      Bf[c][t2] = Bv[(c * 8 + w * 2 + t2) * 64 + lane];
  float bias0 = bfull[w * 32 + nloc];
  float bias1 = bfull[w * 32 + 16 + nloc];

  float A0 = 0.f, B0 = 0.f, A1 = 0.f, B1 = 0.f;
  if (ACT){
    const float invR = 1.f / (float)(NATOM * MNBR);
    float m0 = sum1[lane] * invR;
    float v0 = fmaxf(sq1[lane] * invR - m0 * m0, 0.f);
    A0 = g1[lane] * rsqrtf(v0 + 1e-5f);  B0 = be1[lane] - m0 * A0;
    float m1 = sum1[64 + lane] * invR;
    float v1 = fmaxf(sq1[64 + lane] * invR - m1 * m1, 0.f);
    A1 = g1[64 + lane] * rsqrtf(v1 + 1e-5f);  B1 = be1[64 + lane] - m1 * A1;
  }
  float sAcc0 = 0.f, sAcc1 = 0.f, qAcc0 = 0.f, qAcc1 = 0.f;
  if (tid < (ACT ? 64 : 128)){ redS[tid] = 0.f; redQ[tid] = 0.f; }

  // per-thread staging parameters (identical math to R10, verified)
  const char* xh8   = (const char*)xh;
  const char* bpad8 = (const char*)bond_pad;
  const int jx1 = tid - 64;                    // S1 xnbr chunks [0,192)
  const int rA  = (tid >= 64) ? ((jx1 >> 7) * 16 + (jx1 & 15)) : 0;
  const int cg1 = (tid >= 64) ? ((((jx1 >> 6) & 1) * 4 + ((jx1 >> 4) & 3)) * 16) : 0;
  const int jx2 = tid + 192;                   // S2 xnbr chunks [192,384)
  const int rB  = (tid < 192) ? ((jx2 >> 7) * 16 + (jx2 & 15)) : 0;
  const int cg2 = (tid < 192) ? ((((jx2 >> 6) & 1) * 4 + ((jx2 >> 4) & 3)) * 16) : 0;

  uint4 rb = {0,0,0,0}, r1 = {0,0,0,0}, r2 = {0,0,0,0};

#define STAGE_LOAD(SS)                                                           \
  {                                                                              \
    rb = *(const uint4*)(bpad8 + (size_t)(SS) * 4608 + (size_t)tid * 16);        \
    const char* p1;                                                              \
    if (tid < 32)      p1 = bpad8 + (size_t)(SS) * 4608 + (size_t)(tid + 256) * 16; \
    else if (tid < 64) p1 = xh8 + (size_t)(SS) * 512 + (size_t)(tid - 32) * 16;  \
    else               p1 = xh8 + (size_t)nbA * 128 + cg1;                       \
    r1 = *(const uint4*)p1;                                                      \
    if (tid < 192) r2 = *(const uint4*)(xh8 + (size_t)nbB * 128 + cg2);          \
  }
#define STAGE_WRITE(DBUF)                                                        \
  {                                                                              \
    *(uint4*)((DBUF) + tid * 16) = rb;                                           \
    *(uint4*)((DBUF) + 4096 + tid * 16) = r1;                                    \
    if (tid < 192) *(uint4*)((DBUF) + 8192 + tid * 16) = r2;                     \
  }

  const bf16x8 zero8 = {0,0,0,0,0,0,0,0};
  const int s0 = blockIdx.x;

  // prologue: stage s0, prefetch indices for s0+CGRID
  int nbA = nbr_idx[s0 * 48 + rA];
  int nbB = nbr_idx[s0 * 48 + rB];
  STAGE_LOAD(s0);
  STAGE_WRITE(stg);
  nbA = nbr_idx[(s0 + CGRID) * 48 + rA];
  nbB = nbr_idx[(s0 + CGRID) * 48 + rB];
  __syncthreads();   // buf0 ready

  for (int k = 0; k < 5; k++){
    const int s = s0 + k * CGRID;
    char* cb   = stg + (k & 1) * 11264;
    char* nbuf = stg + ((k & 1) ^ 1) * 11264;
    // issue next-supertile loads NOW; they land under the MFMA(+ACT) phase
    if (k < 4) STAGE_LOAD(s + CGRID);
    #pragma unroll
    for (int et = 0; et < 3; et++){
      int naloc = (et * 16 + nloc) / 12;
      const char* xs = cb + 4608 + naloc * 128;
      bf16x8 a0 = *(const bf16x8*)(xs + q * 16);
      bf16x8 a1 = *(const bf16x8*)(xs + 64 + q * 16);
      bf16x8 a2 = *(const bf16x8*)(cb + 5120 + (et * 128 + lane) * 16);
      bf16x8 a3 = *(const bf16x8*)(cb + 5120 + (et * 128 + 64 + lane) * 16);
      bf16x8 a4 = *(const bf16x8*)(cb + (et * 96 + lane) * 16);
      bf16x8 a5 = (lane < 32) ? *(const bf16x8*)(cb + (et * 96 + 64 + lane) * 16)
                              : zero8;
      #pragma unroll
      for (int t2 = 0; t2 < 2; t2++){
        float bs = t2 ? bias1 : bias0;
        f32x4 acc = {bs, bs, bs, bs};
        acc = __builtin_amdgcn_mfma_f32_16x16x32_bf16(a0, Bf[0][t2], acc, 0, 0, 0);
        acc = __builtin_amdgcn_mfma_f32_16x16x32_bf16(a1, Bf[1][t2], acc, 0, 0, 0);
        acc = __builtin_amdgcn_mfma_f32_16x16x32_bf16(a2, Bf[2][t2], acc, 0, 0, 0);
        acc = __builtin_amdgcn_mfma_f32_16x16x32_bf16(a3, Bf[3][t2], acc, 0, 0, 0);
        acc = __builtin_amdgcn_mfma_f32_16x16x32_bf16(a4, Bf[4][t2], acc, 0, 0, 0);
        acc = __builtin_amdgcn_mfma_f32_16x16x32_bf16(a5, Bf[5][t2], acc, 0, 0, 0);
        if (ACT){
          int col = w * 32 + t2 * 16 + nloc;
          int r0 = et * 16 + q * 4;
          gbuf[(r0 + 0) * GS + col] = acc[0];
          gbuf[(r0 + 1) * GS + col] = acc[1];
          gbuf[(r0 + 2) * GS + col] = acc[2];
          gbuf[(r0 + 3) * GS + col] = acc[3];
        } else {
          float ss = acc[0] + acc[1] + acc[2] + acc[3];
          float qq = acc[0]*acc[0] + acc[1]*acc[1] + acc[2]*acc[2] + acc[3]*acc[3];
          if (t2){ sAcc1 += ss; qAcc1 += qq; } else { sAcc0 += ss; qAcc0 += qq; }
        }
      }
    }
    if (ACT){
      // gbuf ready: drain LDS only, raw barrier (staging global loads for
      // s+1 stay in flight and land under the ACT phase below)
      __builtin_amdgcn_sched_barrier(0);
      asm volatile("s_waitcnt lgkmcnt(0)");
      __builtin_amdgcn_s_barrier();
      __builtin_amdgcn_sched_barrier(0);
      float p = 0.f;
      #pragma unroll
      for (int m = 0; m < 12; m++){
        int el = w * 12 + m;
        float u = fmaf(gbuf[el * GS + lane],      A0, B0);
        float v = fmaf(gbuf[el * GS + 64 + lane], A1, B1);
        p = fmaf(sigmoid_fast(u), softplus_fast(v), p);
      }
      summed[(s * 4 + w) * 64 + lane] = p;
      sAcc0 += p;  qAcc0 = fmaf(p, p, qAcc0);
    }
    // commit staged regs to the other buffer (implicit vmcnt waits here,
    // at the latest possible point), prefetch indices 2 ahead
    if (k < 4){
      STAGE_WRITE(nbuf);
      if (k < 3){
        nbA = nbr_idx[(s + 2 * CGRID) * 48 + rA];
        nbB = nbr_idx[(s + 2 * CGRID) * 48 + rB];
      }
    }
    // end-of-iteration: LDS-only drain + raw barrier (no vmcnt drain)
    __builtin_amdgcn_sched_barrier(0);
    asm volatile("s_waitcnt lgkmcnt(0)");
    __builtin_amdgcn_s_barrier();
    __builtin_amdgcn_sched_barrier(0);
  }
#undef STAGE_LOAD
#undef STAGE_WRITE

  if (ACT){
    atomicAdd(&redS[lane], sAcc0);
    atomicAdd(&redQ[lane], qAcc0);
    __syncthreads();
    if (tid < 64){ atomicAdd(&o_sum[tid], redS[tid]); atomicAdd(&o_sq[tid], redQ[tid]); }
  } else {
    int c0 = w * 32 + nloc;
    atomicAdd(&redS[c0], sAcc0);       atomicAdd(&redQ[c0], qAcc0);
    atomicAdd(&redS[c0 + 16], sAcc1);  atomicAdd(&redQ[c0 + 16], qAcc1);
    __syncthreads();
    if (tid < 128){ atomicAdd(&o_sum[tid], redS[tid]); atomicAdd(&o_sq[tid], redQ[tid]); }
  }
}

// R7 fallback conv pass (small-ws path; reads raw nbr_fea, no bond_pad).
template<int ACT>
__global__ __launch_bounds__(256, 3) void conv_mfma(
    const u16* __restrict__ xh, const void* __restrict__ nbr_fea,
    const int* __restrict__ nbr_idx, const u16* __restrict__ wbf_l,
    const float* __restrict__ bfull, const float* __restrict__ sum1,
    const float* __restrict__ sq1, const float* __restrict__ g1,
    const float* __restrict__ be1, float* __restrict__ summed,
    float* __restrict__ o_sum, float* __restrict__ o_sq,
    const int* __restrict__ flag){
  extern __shared__ char smem[];
  u16*   fragA = (u16*)smem;                      // 6*512 u16
  float* gbuf  = (float*)(smem + 6144);           // ACT only: 48*GS
  float* redS  = ACT ? (gbuf + 48 * GS) : (float*)(smem + 6144);
  float* redQ  = redS + (ACT ? 64 : 128);

  const int tid = threadIdx.x;
  const int w = tid >> 6, lane = tid & 63;
  const int q = lane >> 4, nloc = lane & 15, q8 = q * 8;
  const int isbf = *flag;

  bf16x8 Bf[6][2];
  const bf16x8* Bv = (const bf16x8*)wbf_l;
  #pragma unroll
  for (int c = 0; c < 6; c++)
    #pragma unroll
    for (int t2 = 0; t2 < 2; t2++)
      Bf[c][t2] = Bv[(c * 8 + w * 2 + t2) * 64 + lane];
  float bias0 = bfull[w * 32 + nloc];
  float bias1 = bfull[w * 32 + 16 + nloc];

  float A0 = 0.f, B0 = 0.f, A1 = 0.f, B1 = 0.f;
  if (ACT){
    const float invR = 1.f / (float)(NATOM * MNBR);
    float m0 = sum1[lane] * invR;
    float v0 = fmaxf(sq1[lane] * invR - m0 * m0, 0.f);
    A0 = g1[lane] * rsqrtf(v0 + 1e-5f);  B0 = be1[lane] - m0 * A0;
    float m1 = sum1[64 + lane] * invR;
    float v1 = fmaxf(sq1[64 + lane] * invR - m1 * m1, 0.f);
    A1 = g1[64 + lane] * rsqrtf(v1 + 1e-5f);  B1 = be1[64 + lane] - m1 * A1;
  }
  float sAcc0 = 0.f, sAcc1 = 0.f, qAcc0 = 0.f, qAcc1 = 0.f;
  if (tid < (ACT ? 64 : 128)){ redS[tid] = 0.f; redQ[tid] = 0.f; }

  const bf16x8* xv = (const bf16x8*)xh;
  for (int s = blockIdx.x; s < NSUP; s += gridDim.x){
    int e0 = s * 48 + nloc;
    int nb0 = nbr_idx[e0], nb1 = nbr_idx[e0 + 16], nb2 = nbr_idx[e0 + 32];
    bf16x8 Af[3][6];
    if (w < 3){
      size_t eg = (size_t)(s * 48 + w * 16 + nloc);
      u16 v4[8], v5[8];
      if (isbf){
        const u16* br = (const u16*)nbr_fea + eg * 41;
        #pragma unroll
        for (int i = 0; i < 8; i++) v4[i] = br[q8 + i];
        #pragma unroll
        for (int i = 0; i < 8; i++){
          int k5 = 32 + q8 + i;
          v5[i] = (k5 < 41) ? br[k5] : (u16)0;
        }
      } else {
        const float* br = (const float*)nbr_fea + eg * 41;
        #pragma unroll
        for (int i = 0; i < 8; i++) v4[i] = f2bf(br[q8 + i]);
        #pragma unroll
        for (int i = 0; i < 8; i++){
          int k5 = 32 + q8 + i;
          v5[i] = (k5 < 41) ? f2bf(br[k5]) : (u16)0;
        }
      }
      *(uint4*)&fragA[(w * 2 + 0) * 512 + lane * 8] = *(uint4*)v4;
      *(uint4*)&fragA[(w * 2 + 1) * 512 + lane * 8] = *(uint4*)v5;
    }
    __syncthreads();
    #pragma unroll
    for (int et = 0; et < 3; et++){
      int nb = (et == 0) ? nb0 : (et == 1) ? nb1 : nb2;
      int na = s * 4 + (et * 16 + nloc) / 12;
      Af[et][0] = xv[na * 8 + q];
      Af[et][1] = xv[na * 8 + 4 + q];
      Af[et][2] = xv[nb * 8 + q];
      Af[et][3] = xv[nb * 8 + 4 + q];
      Af[et][4] = *(bf16x8*)&fragA[(et * 2 + 0) * 512 + lane * 8];
      Af[et][5] = *(bf16x8*)&fragA[(et * 2 + 1) * 512 + lane * 8];
    }
    #pragma unroll
    for (int et = 0; et < 3; et++){
      #pragma unroll
      for (int t2 = 0; t2 < 2; t2++){
        float bs = t2 ? bias1 : bias0;
        f32x4 acc = {bs, bs, bs, bs};
        acc = __builtin_amdgcn_mfma_f32_16x16x32_bf16(Af[et][0], Bf[0][t2], acc, 0, 0, 0);
        acc = __builtin_amdgcn_mfma_f32_16x16x32_bf16(Af[et][1], Bf[1][t2], acc, 0, 0, 0);
        acc = __builtin_amdgcn_mfma_f32_16x16x32_bf16(Af[et][2], Bf[2][t2], acc, 0, 0, 0);
        acc = __builtin_amdgcn_mfma_f32_16x16x32_bf16(Af[et][3], Bf[3][t2], acc, 0, 0, 0);
        acc = __builtin_amdgcn_mfma_f32_16x16x32_bf16(Af[et][4], Bf[4][t2], acc, 0, 0, 0);
        acc = __builtin_amdgcn_mfma_f32_16x16x32_bf16(Af[et][5], Bf[5][t2], acc, 0, 0, 0);
        if (ACT){
          int col = w * 32 + t2 * 16 + nloc;
          int r0 = et * 16 + q * 4;
          gbuf[(r0 + 0) * GS + col] = acc[0];
          gbuf[(r0 + 1) * GS + col] = acc[1];
          gbuf[(r0 + 2) * GS + col] = acc[2];
          gbuf[(r0 + 3) * GS + col] = acc[3];
        } else {
          float ss = acc[0] + acc[1] + acc[2] + acc[3];
          float qq = acc[0]*acc[0] + acc[1]*acc[1] + acc[2]*acc[2] + acc[3]*acc[3];
          if (t2){ sAcc1 += ss; qAcc1 += qq; } else { sAcc0 += ss; qAcc0 += qq; }
        }
      }
    }
    if (ACT){
      __syncthreads();
      float p = 0.f;
      #pragma unroll
      for (int m = 0; m < 12; m++){
        int el = w * 12 + m;
        float u = fmaf(gbuf[el * GS + lane],      A0, B0);
        float v = fmaf(gbuf[el * GS + 64 + lane], A1, B1);
        p = fmaf(sigmoid_fast(u), softplus_fast(v), p);
      }
      summed[(s * 4 + w) * 64 + lane] = p;
      sAcc0 += p;  qAcc0 = fmaf(p, p, qAcc0);
    }
    __syncthreads();
  }
  if (ACT){
    atomicAdd(&redS[lane], sAcc0);
    atomicAdd(&redQ[lane], qAcc0);
    __syncthreads();
    if (tid < 64){ atomicAdd(&o_sum[tid], redS[tid]); atomicAdd(&o_sq[tid], redQ[tid]); }
  } else {
    int c0 = w * 32 + nloc;
    atomicAdd(&redS[c0], sAcc0);       atomicAdd(&redQ[c0], qAcc0);
    atomicAdd(&redS[c0 + 16], sAcc1);  atomicAdd(&redQ[c0 + 16], qAcc1);
    __syncthreads();
    if (tid < 128){ atomicAdd(&o_sum[tid], redS[tid]); atomicAdd(&o_sq[tid], redQ[tid]); }
  }
}

__global__ __launch_bounds__(256) void update_x_kernel(
    float* __restrict__ x, u16* __restrict__ xh,
    const float* __restrict__ summed,
    const float* __restrict__ sum2, const float* __restrict__ sq2,
    const float* __restrict__ g2, const float* __restrict__ be2){
  int idx = blockIdx.x * 256 + threadIdx.x;
  int f = idx & 63;
  const float invN = 1.f / (float)NATOM;
  float mean = sum2[f] * invN;
  float var  = fmaxf(sq2[f] * invN - mean * mean, 0.f);
  float a = g2[f] * rsqrtf(var + 1e-5f);
  float b = be2[f] - mean * a;
  float v = x[idx] + fmaf(summed[idx], a, b);
  float r = softplusf_(v);
  x[idx] = r;
  xh[idx] = f2bf(r);
}

__global__ __launch_bounds__(256) void pool_kernel(
    const float* __restrict__ x, const int* __restrict__ cidx,
    float* __restrict__ crys, float* __restrict__ cnt){
  int idx = blockIdx.x * 256 + threadIdx.x;
  int n = idx >> 6, f = idx & 63;
  int c = cidx[n];
  atomicAdd(&crys[c * FD + f], x[idx]);
  if (f == 0) atomicAdd(&cnt[c], 1.f);
}

__global__ __launch_bounds__(128) void head_kernel(
    const float* __restrict__ crys, const float* __restrict__ cnt,
    const float* __restrict__ W_fc, const float* __restrict__ b_fc,
    const float* __restrict__ W_out, const float* __restrict__ b_out,
    void* __restrict__ out, const int* __restrict__ flag){
  __shared__ float p_s[FD];
  __shared__ float red_s[HD];
  int c = blockIdx.x, tid = threadIdx.x;
  if (tid < FD){
    float ct = fmaxf(cnt[c], 1.f);
    p_s[tid] = softplusf_(crys[c * FD + tid] / ct);
  }
  __syncthreads();
  float acc = b_fc[tid];
  for (int k = 0; k < FD; k++)
    acc = fmaf(p_s[k], W_fc[k * HD + tid], acc);
  float h = softplusf_(acc);
  red_s[tid] = h * W_out[tid];
  __syncthreads();
  for (int s = HD / 2; s > 0; s >>= 1){
    if (tid < s) red_s[tid] += red_s[tid + s];
    __syncthreads();
  }
  if (tid == 0){
    float r = red_s[0] + b_out[0];
    if (*flag) ((u16*)out)[c] = f2bf(r);
    else       ((float*)out)[c] = r;
  }
}

extern "C" void kernel_launch(void* const* d_in, const int* in_sizes, int n_in,
                              void* d_out, int out_size, void* d_ws, size_t ws_size,
                              hipStream_t stream){
  if (ws_size < WS_NEED_BYTES) return;  // diagnostic: leaves d_out zeroed
  const bool full = (ws_size >= WS_FULL_BYTES);
  const void* atom_fea = d_in[0];
  const void* nbr_fea  = d_in[1];
  const int* nbr_idx   = (const int*)d_in[2];
  const int* cidx      = (const int*)d_in[3];

  float* ws     = (float*)d_ws;
  float* x      = ws + OFF_X;
  u16*   xh     = (u16*)(ws + OFF_XH);
  float* summed = ws + OFF_SUMMED;
  float* sum1   = ws + OFF_STATS;
  float* sq1    = sum1 + 128;
  float* sum2   = sq1 + 128;
  float* sq2    = sum2 + 64;
  float* crys   = ws + OFF_CRYS;
  float* cnt    = ws + OFF_CNT;
  float* wc     = ws + OFF_WCONV;
  u16*   wbf    = (u16*)(ws + OFF_WBF);
  int*   flag   = (int*)(ws + OFF_FLAG);
  u16*   bpad   = (u16*)(ws + OFF_BPAD);

  detect_kernel<<<1, 64, 0, stream>>>((const u16*)nbr_fea, flag);
  CvtArgs ca;
  const int srcidx[12] = {4,5,6,7,8,9,10,11,12,13,14,15};
  const int starts[13] = {W_EMB_O, B_EMB_O, W_FULL_O, B_FULL_O, G1_O, BE1_O,
                          G2_O, BE2_O, W_FC_O, B_FC_O, W_OUT_O, B_OUT_O, WC_TOTAL};
  for (int i = 0; i < 12; i++){ ca.src[i] = d_in[srcidx[i]]; ca.start[i] = starts[i]; }
  ca.start[12] = WC_TOTAL;
  cvt_all_kernel<<<(WC_TOTAL + 255) / 256, 256, 0, stream>>>(ca, wc, flag);
  build_bfrag<<<(9216 + 255) / 256, 256, 0, stream>>>(wc + W_FULL_O, wbf);
  if (full) bond_prep<<<NSUP, 256, 0, stream>>>(nbr_fea, bpad, flag);

  embed_kernel<<<NATOM / 4, 256, 0, stream>>>(atom_fea, wc + W_EMB_O, wc + B_EMB_O,
                                              x, xh, flag);
  const int LDS_STATS_L = 2 * 11264 + 2 * 128 * 4;              // 23552
  const int LDS_ACT_L   = 2 * 11264 + 48 * GS * 4 + 2 * 64 * 4; // 48384
  const int LDS_STATS_F = 6144 + 2 * 128 * 4;                   // 7168
  const int LDS_ACT_F   = 6144 + (48 * GS + 128) * 4;           // 32000
  for (int i = 0; i < 3; i++){
    const u16* wbf_l = wbf + (size_t)i * 3072 * 8;
    hipMemsetAsync(sum1, 0, 384 * sizeof(float), stream);
    if (full){
      conv_lds<0><<<CGRID, 256, LDS_STATS_L, stream>>>(xh, bpad, nbr_idx,
          wbf_l, wc + B_FULL_O + i * F2D, sum1, sq1, wc + G1_O + i * F2D,
          wc + BE1_O + i * F2D, summed, sum1, sq1);
      conv_lds<1><<<CGRID, 256, LDS_ACT_L, stream>>>(xh, bpad, nbr_idx,
          wbf_l, wc + B_FULL_O + i * F2D, sum1, sq1, wc + G1_O + i * F2D,
          wc + BE1_O + i * F2D, summed, sum2, sq2);
    } else {
      conv_mfma<0><<<CGRID, 256, LDS_STATS_F, stream>>>(xh, nbr_fea, nbr_idx,
          wbf_l, wc + B_FULL_O + i * F2D, sum1, sq1, wc + G1_O + i * F2D,
          wc + BE1_O + i * F2D, summed, sum1, sq1, flag);
      conv_mfma<1><<<CGRID, 256, LDS_ACT_F, stream>>>(xh, nbr_fea, nbr_idx,
          wbf_l, wc + B_FULL_O + i * F2D, sum1, sq1, wc + G1_O + i * F2D,
          wc + BE1_O + i * F2D, summed, sum2, sq2, flag);
    }
    update_x_kernel<<<(NATOM * FD) / 256, 256, 0, stream>>>(x, xh, summed, sum2, sq2,
        wc + G2_O + i * FD, wc + BE2_O + i * FD);
  }
  hipMemsetAsync(crys, 0, (NCRY * FD + NCRY) * sizeof(float), stream);
  pool_kernel<<<(NATOM * FD) / 256, 256, 0, stream>>>(x, cidx, crys, cnt);
  head_kernel<<<NCRY, 128, 0, stream>>>(crys, cnt, wc + W_FC_O, wc + B_FC_O,
      wc + W_OUT_O, wc + B_OUT_O, d_out, flag);
}